// Round 1
// baseline (314.343 us; speedup 1.0000x reference)
//
#include <hip/hip_runtime.h>
#include <math.h>

#define NB 16      // batch
#define NN 4096    // nodes
#define NE 65536   // edges
#define DD 256     // feature dim
#define NR 4       // relations (excl. self)
#define VG 30000
#define VS 20000
#define NBG 118    // ceil(VG/256)
#define NBS 79     // ceil(VS/256)

// ws layout (float offsets):
// ssum  [NB][NR][DD]          @ 0       (16384)
// cnt   [NB][NR] (int)        @ 16384   (64)
// h0T   [DD][NB]              @ 16448   (4096)
// pm    [NB*NBG + NB*NBS]     @ 20544   (3152)
// ps    [NB*NBG + NB*NBS]     @ 23696   (3152)
// L     [2][NB]               @ 26848   (32)
#define WS_SSUM 0
#define WS_CNT  16384
#define WS_H0T  16448
#define WS_PM   20544
#define WS_PS   23696
#define WS_L    26848

__global__ __launch_bounds__(256) void k_scan(
    const int* __restrict__ ei, const int* __restrict__ etp,
    const float* __restrict__ x,
    float* __restrict__ ssum, int* __restrict__ cnt) {
  const int b = blockIdx.x;
  const int* src = ei + (size_t)b * 2 * NE;
  const int* dst = src + NE;
  const int* etb = etp + (size_t)b * NE;
  const int per = NE / gridDim.y;
  const int e0 = blockIdx.y * per;
  for (int e = e0 + threadIdx.x; e < e0 + per; e += blockDim.x) {
    if (src[e] == 0) {
      const int r = etb[e];
      const int j = dst[e];
      atomicAdd(&cnt[b * NR + r], 1);
      const float* xr = x + ((size_t)b * NN + j) * DD;
      float* sr = ssum + ((size_t)b * NR + r) * DD;
#pragma unroll 4
      for (int k = 0; k < DD; ++k) atomicAdd(&sr[k], xr[k]);
    }
  }
}

__global__ __launch_bounds__(256) void k_h0(
    const float* __restrict__ x, const float* __restrict__ W_all,
    const float* __restrict__ ssum, const int* __restrict__ cnt,
    float* __restrict__ h0T) {
  const int b = blockIdx.x;
  const int j = threadIdx.x;  // 0..255 output dim
  __shared__ float u[NR + 1][DD];
  u[0][j] = x[((size_t)b * NN + 0) * DD + j];
#pragma unroll
  for (int r = 0; r < NR; ++r) {
    float cinv = 1.0f / fmaxf((float)cnt[b * NR + r], 1.0f);
    u[r + 1][j] = ssum[((size_t)b * NR + r) * DD + j] * cinv;
  }
  __syncthreads();
  float acc = 0.f;
  for (int r = 0; r <= NR; ++r) {
    const float* W = W_all + (size_t)r * DD * DD;
#pragma unroll 8
    for (int k = 0; k < DD; ++k) acc += u[r][k] * W[k * DD + j];
  }
  h0T[j * NB + b] = fmaxf(acc, 0.f);  // ReLU, transposed store
}

__global__ __launch_bounds__(256) void k_logits(
    const float* __restrict__ Wg, const float* __restrict__ bg,
    const float* __restrict__ Ws, const float* __restrict__ bs,
    const float* __restrict__ h0T, float* __restrict__ out,
    float* __restrict__ pm, float* __restrict__ ps) {
  const int blk = blockIdx.x;
  int tile, V, nblk;
  const float *W, *bias;
  float *o, *pmh, *psh;
  if (blk < NBG) {
    tile = blk; V = VG; W = Wg; bias = bg; o = out;
    pmh = pm; psh = ps; nblk = NBG;
  } else {
    tile = blk - NBG; V = VS; W = Ws; bias = bs; o = out + (size_t)NB * VG;
    pmh = pm + NB * NBG; psh = ps + NB * NBG; nblk = NBS;
  }
  const int v = tile * 256 + threadIdx.x;
  const bool valid = (v < V);
  float acc[NB];
  float bb = valid ? bias[v] : 0.f;
#pragma unroll
  for (int b = 0; b < NB; ++b) acc[b] = bb;
  if (valid) {
    for (int k = 0; k < DD; ++k) {
      float w = W[(size_t)k * V + v];
#pragma unroll
      for (int b = 0; b < NB; ++b) acc[b] += h0T[k * NB + b] * w;
    }
#pragma unroll
    for (int b = 0; b < NB; ++b) o[(size_t)b * V + v] = acc[b];
  }
  // per-block (max, sum-exp) partials per graph
  __shared__ float redm[4][NB];
  __shared__ float reds[4][NB];
  const int lane = threadIdx.x & 63;
  const int wave = threadIdx.x >> 6;
#pragma unroll
  for (int b = 0; b < NB; ++b) {
    float m = valid ? acc[b] : -INFINITY;
    for (int off = 32; off > 0; off >>= 1) m = fmaxf(m, __shfl_xor(m, off));
    float sx = valid ? __expf(acc[b] - m) : 0.f;
    for (int off = 32; off > 0; off >>= 1) sx += __shfl_xor(sx, off);
    if (lane == 0) { redm[wave][b] = m; reds[wave][b] = sx; }
  }
  __syncthreads();
  if (threadIdx.x < NB) {
    const int b = threadIdx.x;
    float M = -INFINITY;
#pragma unroll
    for (int wv = 0; wv < 4; ++wv) M = fmaxf(M, redm[wv][b]);
    float S = 0.f;
#pragma unroll
    for (int wv = 0; wv < 4; ++wv) {
      float mi = redm[wv][b];
      S += (mi > -INFINITY) ? reds[wv][b] * __expf(mi - M) : 0.f;
    }
    pmh[b * nblk + tile] = M;
    psh[b * nblk + tile] = S;
  }
}

__global__ __launch_bounds__(1024) void k_reduce(
    const float* __restrict__ pm, const float* __restrict__ ps,
    float* __restrict__ L) {
  const int gtid = blockIdx.x * 1024 + threadIdx.x;
  const int w = gtid >> 6;      // 0..31
  const int lane = gtid & 63;
  const int head = w >> 4;      // 0: g, 1: s
  const int b = w & 15;
  const float* pmh = pm + (head ? NB * NBG : 0);
  const float* psh = ps + (head ? NB * NBG : 0);
  const int nblk = head ? NBS : NBG;
  float m = -INFINITY, s = 0.f;
  for (int i = lane; i < nblk; i += 64) {
    float mi = pmh[b * nblk + i];
    float si = psh[b * nblk + i];
    float Mn = fmaxf(m, mi);
    float sn = ((m > -INFINITY) ? s * __expf(m - Mn) : 0.f) +
               ((mi > -INFINITY) ? si * __expf(mi - Mn) : 0.f);
    m = Mn; s = sn;
  }
  for (int off = 32; off > 0; off >>= 1) {
    float mo = __shfl_xor(m, off);
    float so = __shfl_xor(s, off);
    float Mn = fmaxf(m, mo);
    float sn = ((m > -INFINITY) ? s * __expf(m - Mn) : 0.f) +
               ((mo > -INFINITY) ? so * __expf(mo - Mn) : 0.f);
    m = Mn; s = sn;
  }
  if (lane == 0) L[head * NB + b] = m + logf(s);
}

__global__ __launch_bounds__(256) void k_final(
    float* __restrict__ out, const float* __restrict__ L) {
  const size_t i = (size_t)blockIdx.x * 256 + threadIdx.x;
  const size_t total = (size_t)NB * (VG + VS);
  if (i >= total) return;
  int head, b;
  if (i < (size_t)NB * VG) { head = 0; b = (int)(i / VG); }
  else { head = 1; b = (int)((i - (size_t)NB * VG) / VS); }
  out[i] -= L[head * NB + b];
}

extern "C" void kernel_launch(void* const* d_in, const int* in_sizes, int n_in,
                              void* d_out, int out_size, void* d_ws, size_t ws_size,
                              hipStream_t stream) {
  const float* x     = (const float*)d_in[0];
  const float* W_all = (const float*)d_in[1];
  const float* Wg    = (const float*)d_in[2];
  const float* bg    = (const float*)d_in[3];
  const float* Ws    = (const float*)d_in[4];
  const float* bs    = (const float*)d_in[5];
  const int*   ei    = (const int*)d_in[6];
  const int*   etp   = (const int*)d_in[7];
  float* out = (float*)d_out;
  float* ws  = (float*)d_ws;

  float* ssum = ws + WS_SSUM;
  int*   cnt  = (int*)(ws + WS_CNT);
  float* h0T  = ws + WS_H0T;
  float* pm   = ws + WS_PM;
  float* ps   = ws + WS_PS;
  float* L    = ws + WS_L;

  // zero sums + counts (ws is poisoned before every launch)
  hipMemsetAsync(d_ws, 0, (16384 + 64) * sizeof(float), stream);

  dim3 gscan(NB, 16);
  k_scan<<<gscan, 256, 0, stream>>>(ei, etp, x, ssum, cnt);
  k_h0<<<NB, 256, 0, stream>>>(x, W_all, ssum, cnt, h0T);
  k_logits<<<NBG + NBS, 256, 0, stream>>>(Wg, bg, Ws, bs, h0T, out, pm, ps);
  k_reduce<<<2, 1024, 0, stream>>>(pm, ps, L);
  k_final<<<(NB * (VG + VS) + 255) / 256, 256, 0, stream>>>(out, L);
}

// Round 2
// 197.100 us; speedup vs baseline: 1.5948x; 1.5948x over previous
//
#include <hip/hip_runtime.h>
#include <math.h>

#define NB 16      // batch
#define NN 4096    // nodes
#define NE 65536   // edges
#define DD 256     // feature dim
#define NR 4       // relations (excl. self)
#define VG 30000
#define VS 20000
#define NBG 118    // ceil(VG/256)
#define NBS 79     // ceil(VS/256)
#define MCAP 1024  // match-list capacity per graph (E[matches] = 16)

// ws layout (float offsets):
#define WS_MC   0       // mcount [NB] int                 (16)
#define WS_CNT  16      // cnt [NB][NR] int                (64)
#define WS_H0A  80      // h0acc [NB][DD]                  (4096)
#define WS_H0T  4176    // h0T [DD][NB]                    (4096)
#define WS_MAT  8272    // matches [NB][MCAP] int          (16384)
#define WS_PM   24656   // per-block max partials          (3152)
#define WS_PS   27808   // per-block sumexp partials       (3152)
#define WS_L    30960   // logsumexp [2][NB]               (32)
// total 30992 floats = 124 KB

__global__ __launch_bounds__(256) void k_scan(
    const int* __restrict__ ei, const int* __restrict__ etp,
    int* __restrict__ mcount, int* __restrict__ cnt, int* __restrict__ matches) {
  const int b = blockIdx.x;
  const int* src = ei + (size_t)b * 2 * NE;
  const int* dst = src + NE;
  const int* etb = etp + (size_t)b * NE;
  const int per = NE / gridDim.y;   // 4096
  const int base = blockIdx.y * per;
  for (int e0 = base + threadIdx.x * 4; e0 < base + per; e0 += blockDim.x * 4) {
    const int4 s = *reinterpret_cast<const int4*>(&src[e0]);
#pragma unroll
    for (int u = 0; u < 4; ++u) {
      const int sv = (u == 0) ? s.x : (u == 1) ? s.y : (u == 2) ? s.z : s.w;
      if (sv == 0) {
        const int e = e0 + u;
        const int r = etb[e];
        const int j = dst[e];
        atomicAdd(&cnt[b * NR + r], 1);
        const int idx = atomicAdd(&mcount[b], 1);
        if (idx < MCAP) matches[b * MCAP + idx] = (r << 12) | j;
      }
    }
  }
}

// grid (NB, NR+1): block (b, r) computes u_r @ W_all[r] and atomicAdds into h0acc[b]
__global__ __launch_bounds__(256) void k_h0(
    const float* __restrict__ x, const float* __restrict__ W_all,
    const int* __restrict__ mcount, const int* __restrict__ cnt,
    const int* __restrict__ matches, float* __restrict__ h0acc) {
  const int b = blockIdx.x;
  const int r = blockIdx.y;   // 0 = self, 1..NR = relation r-1
  const int j = threadIdx.x;
  __shared__ float u[DD];
  if (r == 0) {
    u[j] = x[((size_t)b * NN) * DD + j];
  } else {
    float s = 0.f;
    const int n = min(mcount[b], MCAP);
    for (int m = 0; m < n; ++m) {
      const int mv = matches[b * MCAP + m];
      if ((mv >> 12) == r - 1) s += x[((size_t)b * NN + (mv & 4095)) * DD + j];
    }
    const float cinv = 1.0f / fmaxf((float)cnt[b * NR + (r - 1)], 1.0f);
    u[j] = s * cinv;
  }
  __syncthreads();
  const float* W = W_all + (size_t)r * DD * DD;
  float acc = 0.f;
#pragma unroll 2
  for (int k0 = 0; k0 < DD; k0 += 8) {
    float w[8];
#pragma unroll
    for (int q = 0; q < 8; ++q) w[q] = W[(k0 + q) * DD + j];
#pragma unroll
    for (int q = 0; q < 8; ++q) acc = fmaf(u[k0 + q], w[q], acc);
  }
  atomicAdd(&h0acc[b * DD + j], acc);
}

__global__ __launch_bounds__(256) void k_h0fin(
    const float* __restrict__ h0acc, float* __restrict__ h0T) {
  const int b = blockIdx.x;
  const int j = threadIdx.x;
  h0T[j * NB + b] = fmaxf(h0acc[b * DD + j], 0.f);
}

__global__ __launch_bounds__(256) void k_logits(
    const float* __restrict__ Wg, const float* __restrict__ bg,
    const float* __restrict__ Ws, const float* __restrict__ bs,
    const float* __restrict__ h0T, float* __restrict__ out,
    float* __restrict__ pm, float* __restrict__ ps) {
  const int blk = blockIdx.x;
  int tile, V, nblk;
  const float *W, *bias;
  float *o, *pmh, *psh;
  if (blk < NBG) {
    tile = blk; V = VG; W = Wg; bias = bg; o = out;
    pmh = pm; psh = ps; nblk = NBG;
  } else {
    tile = blk - NBG; V = VS; W = Ws; bias = bs; o = out + (size_t)NB * VG;
    pmh = pm + NB * NBG; psh = ps + NB * NBG; nblk = NBS;
  }
  const int v = tile * 256 + threadIdx.x;
  const bool valid = (v < V);
  const int vc = valid ? v : (V - 1);   // clamp so loads always issue
  float acc[NB];
  const float bb = bias[vc];
#pragma unroll
  for (int b = 0; b < NB; ++b) acc[b] = bb;
  const float* Wv = W + vc;
#pragma unroll 2
  for (int k0 = 0; k0 < DD; k0 += 16) {
    float w[16];
#pragma unroll
    for (int u = 0; u < 16; ++u) w[u] = Wv[(size_t)(k0 + u) * V];
#pragma unroll
    for (int u = 0; u < 16; ++u) {
#pragma unroll
      for (int b = 0; b < NB; ++b)
        acc[b] = fmaf(h0T[(k0 + u) * NB + b], w[u], acc[b]);  // h0T uniform -> s_load
    }
  }
  if (valid) {
#pragma unroll
    for (int b = 0; b < NB; ++b) o[(size_t)b * V + v] = acc[b];
  }
  // per-block (max, sum-exp) partials per graph
  __shared__ float redm[4][NB];
  __shared__ float reds[4][NB];
  const int lane = threadIdx.x & 63;
  const int wave = threadIdx.x >> 6;
#pragma unroll
  for (int b = 0; b < NB; ++b) {
    float m = valid ? acc[b] : -INFINITY;
    for (int off = 32; off > 0; off >>= 1) m = fmaxf(m, __shfl_xor(m, off));
    float sx = valid ? __expf(acc[b] - m) : 0.f;
    for (int off = 32; off > 0; off >>= 1) sx += __shfl_xor(sx, off);
    if (lane == 0) { redm[wave][b] = m; reds[wave][b] = sx; }
  }
  __syncthreads();
  if (threadIdx.x < NB) {
    const int b = threadIdx.x;
    float M = -INFINITY;
#pragma unroll
    for (int wv = 0; wv < 4; ++wv) M = fmaxf(M, redm[wv][b]);
    float S = 0.f;
#pragma unroll
    for (int wv = 0; wv < 4; ++wv) {
      float mi = redm[wv][b];
      S += (mi > -INFINITY) ? reds[wv][b] * __expf(mi - M) : 0.f;
    }
    pmh[b * nblk + tile] = M;
    psh[b * nblk + tile] = S;
  }
}

__global__ __launch_bounds__(1024) void k_reduce(
    const float* __restrict__ pm, const float* __restrict__ ps,
    float* __restrict__ L) {
  const int gtid = blockIdx.x * 1024 + threadIdx.x;
  const int w = gtid >> 6;      // 0..31
  const int lane = gtid & 63;
  const int head = w >> 4;      // 0: g, 1: s
  const int b = w & 15;
  const float* pmh = pm + (head ? NB * NBG : 0);
  const float* psh = ps + (head ? NB * NBG : 0);
  const int nblk = head ? NBS : NBG;
  float m = -INFINITY, s = 0.f;
  for (int i = lane; i < nblk; i += 64) {
    float mi = pmh[b * nblk + i];
    float si = psh[b * nblk + i];
    float Mn = fmaxf(m, mi);
    float sn = ((m > -INFINITY) ? s * __expf(m - Mn) : 0.f) +
               ((mi > -INFINITY) ? si * __expf(mi - Mn) : 0.f);
    m = Mn; s = sn;
  }
  for (int off = 32; off > 0; off >>= 1) {
    float mo = __shfl_xor(m, off);
    float so = __shfl_xor(s, off);
    float Mn = fmaxf(m, mo);
    float sn = ((m > -INFINITY) ? s * __expf(m - Mn) : 0.f) +
               ((mo > -INFINITY) ? so * __expf(mo - Mn) : 0.f);
    m = Mn; s = sn;
  }
  if (lane == 0) L[head * NB + b] = m + logf(s);
}

__global__ __launch_bounds__(256) void k_final(
    float* __restrict__ out, const float* __restrict__ L) {
  const size_t i = (size_t)blockIdx.x * 256 + threadIdx.x;
  const size_t total = (size_t)NB * (VG + VS);
  if (i >= total) return;
  int head, b;
  if (i < (size_t)NB * VG) { head = 0; b = (int)(i / VG); }
  else { head = 1; b = (int)((i - (size_t)NB * VG) / VS); }
  out[i] -= L[head * NB + b];
}

extern "C" void kernel_launch(void* const* d_in, const int* in_sizes, int n_in,
                              void* d_out, int out_size, void* d_ws, size_t ws_size,
                              hipStream_t stream) {
  const float* x     = (const float*)d_in[0];
  const float* W_all = (const float*)d_in[1];
  const float* Wg    = (const float*)d_in[2];
  const float* bg    = (const float*)d_in[3];
  const float* Ws    = (const float*)d_in[4];
  const float* bs    = (const float*)d_in[5];
  const int*   ei    = (const int*)d_in[6];
  const int*   etp   = (const int*)d_in[7];
  float* out = (float*)d_out;
  float* ws  = (float*)d_ws;

  int*   mcount  = (int*)(ws + WS_MC);
  int*   cnt     = (int*)(ws + WS_CNT);
  float* h0acc   = ws + WS_H0A;
  float* h0T     = ws + WS_H0T;
  int*   matches = (int*)(ws + WS_MAT);
  float* pm      = ws + WS_PM;
  float* ps      = ws + WS_PS;
  float* L       = ws + WS_L;

  // zero mcount + cnt + h0acc (ws is re-poisoned before every launch)
  hipMemsetAsync(d_ws, 0, (16 + 64 + NB * DD) * sizeof(float), stream);

  dim3 gscan(NB, 16);
  k_scan<<<gscan, 256, 0, stream>>>(ei, etp, mcount, cnt, matches);
  dim3 gh0(NB, NR + 1);
  k_h0<<<gh0, 256, 0, stream>>>(x, W_all, mcount, cnt, matches, h0acc);
  k_h0fin<<<NB, 256, 0, stream>>>(h0acc, h0T);
  k_logits<<<NBG + NBS, 256, 0, stream>>>(Wg, bg, Ws, bs, h0T, out, pm, ps);
  k_reduce<<<2, 1024, 0, stream>>>(pm, ps, L);
  k_final<<<(NB * (VG + VS) + 255) / 256, 256, 0, stream>>>(out, L);
}

// Round 4
// 197.027 us; speedup vs baseline: 1.5954x; 1.0004x over previous
//
#include <hip/hip_runtime.h>
#include <math.h>

#define NB 16      // batch
#define NN 4096    // nodes
#define NE 65536   // edges
#define DD 256     // feature dim
#define NR 4       // relations (excl. self)
#define VG 30000
#define VS 20000
#define NBG2 469   // ceil(VG/64)
#define NBS2 313   // ceil(VS/64)
#define MCAP 1024  // match-list capacity per graph (E[matches] = 16)

// ws layout (float offsets):
#define WS_MC   0       // mcount [NB] int                 (16)
#define WS_CNT  16      // cnt [NB][NR] int                (64)
#define WS_H0A  80      // h0acc [NB][DD]                  (4096)
#define WS_U    4176    // u [NB][NR+1][DD]                (20480)
#define WS_H0T  24656   // h0T [DD][NB]                    (4096)
#define WS_MAT  28752   // matches [NB][MCAP] int          (16384)
#define WS_PM   45136   // per-block max partials          (12512)
#define WS_PS   57648   // per-block sumexp partials       (12512)
#define WS_L    70160   // logsumexp [2][NB]               (32)
// total 70192 floats = 281 KB

__global__ __launch_bounds__(256) void k_scan(
    const int* __restrict__ ei, const int* __restrict__ etp,
    int* __restrict__ mcount, int* __restrict__ cnt, int* __restrict__ matches) {
  const int b = blockIdx.x;
  const int* src = ei + (size_t)b * 2 * NE;
  const int* dst = src + NE;
  const int* etb = etp + (size_t)b * NE;
  const int per = NE / gridDim.y;   // 4096
  const int base = blockIdx.y * per;
  for (int e0 = base + threadIdx.x * 4; e0 < base + per; e0 += blockDim.x * 4) {
    const int4 s = *reinterpret_cast<const int4*>(&src[e0]);
#pragma unroll
    for (int u = 0; u < 4; ++u) {
      const int sv = (u == 0) ? s.x : (u == 1) ? s.y : (u == 2) ? s.z : s.w;
      if (sv == 0) {
        const int e = e0 + u;
        const int r = etb[e];
        const int j = dst[e];
        atomicAdd(&cnt[b * NR + r], 1);
        const int idx = atomicAdd(&mcount[b], 1);
        if (idx < MCAP) matches[b * MCAP + idx] = (r << 12) | j;
      }
    }
  }
}

// grid (NB, NR+1): block (b, r) builds aggregated input vector u[b][r][:]
__global__ __launch_bounds__(256) void k_u(
    const float* __restrict__ x, const int* __restrict__ mcount,
    const int* __restrict__ cnt, const int* __restrict__ matches,
    float* __restrict__ u) {
  const int b = blockIdx.x;
  const int r = blockIdx.y;   // 0 = self, 1..NR = relation r-1
  const int k = threadIdx.x;
  float val;
  if (r == 0) {
    val = x[((size_t)b * NN) * DD + k];
  } else {
    float s = 0.f;
    const int n = min(mcount[b], MCAP);
    for (int m = 0; m < n; ++m) {
      const int mv = matches[b * MCAP + m];
      if ((mv >> 12) == r - 1) s += x[((size_t)b * NN + (mv & 4095)) * DD + k];
    }
    s *= 1.0f / fmaxf((float)cnt[b * NR + (r - 1)], 1.0f);
    val = s;
  }
  u[((size_t)b * (NR + 1) + r) * DD + k] = val;
}

// grid (NR+1, 8): block (r, jt) computes u[:, r, :] @ W_all[r][:, jt*32:+32]
// for ALL graphs at once; W is read once total (not once per graph).
__global__ __launch_bounds__(256) void k_h0mm(
    const float* __restrict__ W_all, const float* __restrict__ u,
    float* __restrict__ h0acc) {
  const int r = blockIdx.x;   // 0..NR
  const int jt = blockIdx.y;  // 0..7
  __shared__ float us[NB * DD];       // 16 KB
  __shared__ float red[8][NB][32];    // 16 KB
#pragma unroll
  for (int t = 0; t < 16; ++t) {
    const int flat = t * 256 + threadIdx.x;
    const int b = flat >> 8, k = flat & 255;
    us[flat] = u[((size_t)b * (NR + 1) + r) * DD + k];
  }
  __syncthreads();
  const int jl = threadIdx.x & 31;
  const int kg = threadIdx.x >> 5;    // 0..7, 32 k each
  const int j = jt * 32 + jl;
  const float* W = W_all + (size_t)r * DD * DD + j;
  float acc[NB];
#pragma unroll
  for (int b = 0; b < NB; ++b) acc[b] = 0.f;
  const int kb = kg * 32;
  for (int k0 = 0; k0 < 32; k0 += 8) {
    float w[8];
#pragma unroll
    for (int q = 0; q < 8; ++q) w[q] = W[(size_t)(kb + k0 + q) * DD];
#pragma unroll
    for (int q = 0; q < 8; ++q) {
#pragma unroll
      for (int b = 0; b < NB; ++b)
        acc[b] = fmaf(us[b * DD + kb + k0 + q], w[q], acc[b]);
    }
  }
#pragma unroll
  for (int b = 0; b < NB; ++b) red[kg][b][jl] = acc[b];
  __syncthreads();
  const int bh = threadIdx.x >> 5;  // 0..7
#pragma unroll
  for (int half = 0; half < 2; ++half) {
    const int b = bh + half * 8;
    float s = 0.f;
#pragma unroll
    for (int g = 0; g < 8; ++g) s += red[g][b][jl];
    atomicAdd(&h0acc[b * DD + jt * 32 + jl], s);
  }
}

__global__ __launch_bounds__(256) void k_h0fin(
    const float* __restrict__ h0acc, float* __restrict__ h0T) {
  const int b = blockIdx.x;
  const int j = threadIdx.x;
  h0T[j * NB + b] = fmaxf(h0acc[b * DD + j], 0.f);
}

// grid NBG2+NBS2, 256 thr: 64 v per block, K split across the 4 waves.
__global__ __launch_bounds__(256) void k_logits(
    const float* __restrict__ Wg, const float* __restrict__ bg,
    const float* __restrict__ Ws, const float* __restrict__ bs,
    const float* __restrict__ h0T, float* __restrict__ out,
    float* __restrict__ pm, float* __restrict__ ps) {
  const int blk = blockIdx.x;
  int tile, V, nblk;
  const float *W, *bias;
  float *o, *pmh, *psh;
  if (blk < NBG2) {
    tile = blk; V = VG; W = Wg; bias = bg; o = out;
    pmh = pm; psh = ps; nblk = NBG2;
  } else {
    tile = blk - NBG2; V = VS; W = Ws; bias = bs; o = out + (size_t)NB * VG;
    pmh = pm + NB * NBG2; psh = ps + NB * NBG2; nblk = NBS2;
  }
  const int vl = threadIdx.x & 63;
  const int kq = threadIdx.x >> 6;   // wave id = k-quarter
  const int v = tile * 64 + vl;
  const bool valid = (v < V);
  const int vc = valid ? v : (V - 1);   // clamp so loads always issue
  float acc[NB];
#pragma unroll
  for (int b = 0; b < NB; ++b) acc[b] = 0.f;
  const float* Wv = W + vc;
  const int kbase = kq * 64;
#pragma unroll
  for (int k0 = 0; k0 < 64; k0 += 16) {
    float w[16];
#pragma unroll
    for (int u = 0; u < 16; ++u) w[u] = Wv[(size_t)(kbase + k0 + u) * V];
#pragma unroll
    for (int u = 0; u < 16; ++u) {
#pragma unroll
      for (int b = 0; b < NB; ++b)
        acc[b] = fmaf(h0T[(kbase + k0 + u) * NB + b], w[u], acc[b]);
    }
  }
  __shared__ float red[3][NB][64];   // 12 KB, conflict-free layout
  if (kq > 0) {
#pragma unroll
    for (int b = 0; b < NB; ++b) red[kq - 1][b][vl] = acc[b];
  }
  __syncthreads();
  if (kq == 0) {
    const float bb = bias[vc];
#pragma unroll
    for (int b = 0; b < NB; ++b)
      acc[b] += bb + red[0][b][vl] + red[1][b][vl] + red[2][b][vl];
    if (valid) {
#pragma unroll
      for (int b = 0; b < NB; ++b) o[(size_t)b * V + v] = acc[b];
    }
#pragma unroll
    for (int b = 0; b < NB; ++b) {
      float m = valid ? acc[b] : -INFINITY;
      for (int off = 32; off > 0; off >>= 1) m = fmaxf(m, __shfl_xor(m, off));
      float sx = valid ? __expf(acc[b] - m) : 0.f;
      for (int off = 32; off > 0; off >>= 1) sx += __shfl_xor(sx, off);
      if (vl == 0) { pmh[b * nblk + tile] = m; psh[b * nblk + tile] = sx; }
    }
  }
}

__global__ __launch_bounds__(1024) void k_reduce(
    const float* __restrict__ pm, const float* __restrict__ ps,
    float* __restrict__ L) {
  const int gtid = blockIdx.x * 1024 + threadIdx.x;
  const int w = gtid >> 6;      // 0..31
  const int lane = gtid & 63;
  const int head = w >> 4;      // 0: g, 1: s
  const int b = w & 15;
  const float* pmh = pm + (head ? NB * NBG2 : 0);
  const float* psh = ps + (head ? NB * NBG2 : 0);
  const int nblk = head ? NBS2 : NBG2;
  float m = -INFINITY, s = 0.f;
  for (int i = lane; i < nblk; i += 64) {
    float mi = pmh[b * nblk + i];
    float si = psh[b * nblk + i];
    float Mn = fmaxf(m, mi);
    float sn = ((m > -INFINITY) ? s * __expf(m - Mn) : 0.f) +
               ((mi > -INFINITY) ? si * __expf(mi - Mn) : 0.f);
    m = Mn; s = sn;
  }
  for (int off = 32; off > 0; off >>= 1) {
    float mo = __shfl_xor(m, off);
    float so = __shfl_xor(s, off);
    float Mn = fmaxf(m, mo);
    float sn = ((m > -INFINITY) ? s * __expf(m - Mn) : 0.f) +
               ((mo > -INFINITY) ? so * __expf(mo - Mn) : 0.f);
    m = Mn; s = sn;
  }
  if (lane == 0) L[head * NB + b] = m + logf(s);
}

__global__ __launch_bounds__(256) void k_final(
    float* __restrict__ out, const float* __restrict__ L) {
  const size_t i = (size_t)blockIdx.x * 256 + threadIdx.x;
  const size_t total = (size_t)NB * (VG + VS);
  if (i >= total) return;
  int head, b;
  if (i < (size_t)NB * VG) { head = 0; b = (int)(i / VG); }
  else { head = 1; b = (int)((i - (size_t)NB * VG) / VS); }
  out[i] -= L[head * NB + b];
}

extern "C" void kernel_launch(void* const* d_in, const int* in_sizes, int n_in,
                              void* d_out, int out_size, void* d_ws, size_t ws_size,
                              hipStream_t stream) {
  const float* x     = (const float*)d_in[0];
  const float* W_all = (const float*)d_in[1];
  const float* Wg    = (const float*)d_in[2];
  const float* bg    = (const float*)d_in[3];
  const float* Ws    = (const float*)d_in[4];
  const float* bs    = (const float*)d_in[5];
  const int*   ei    = (const int*)d_in[6];
  const int*   etp   = (const int*)d_in[7];
  float* out = (float*)d_out;
  float* ws  = (float*)d_ws;

  int*   mcount  = (int*)(ws + WS_MC);
  int*   cnt     = (int*)(ws + WS_CNT);
  float* h0acc   = ws + WS_H0A;
  float* u       = ws + WS_U;
  float* h0T     = ws + WS_H0T;
  int*   matches = (int*)(ws + WS_MAT);
  float* pm      = ws + WS_PM;
  float* ps      = ws + WS_PS;
  float* L       = ws + WS_L;

  // zero mcount + cnt + h0acc (ws is re-poisoned before every launch)
  hipMemsetAsync(d_ws, 0, (16 + 64 + NB * DD) * sizeof(float), stream);

  dim3 gscan(NB, 16);
  k_scan<<<gscan, 256, 0, stream>>>(ei, etp, mcount, cnt, matches);
  dim3 gu(NB, NR + 1);
  k_u<<<gu, 256, 0, stream>>>(x, mcount, cnt, matches, u);
  dim3 gmm(NR + 1, 8);
  k_h0mm<<<gmm, 256, 0, stream>>>(W_all, u, h0acc);
  k_h0fin<<<NB, 256, 0, stream>>>(h0acc, h0T);
  k_logits<<<NBG2 + NBS2, 256, 0, stream>>>(Wg, bg, Ws, bs, h0T, out, pm, ps);
  k_reduce<<<2, 1024, 0, stream>>>(pm, ps, L);
  k_final<<<(NB * (VG + VS) + 255) / 256, 256, 0, stream>>>(out, L);
}